// Round 5
// baseline (777.198 us; speedup 1.0000x reference)
//
#include <hip/hip_runtime.h>
#include <cfloat>

typedef _Float16 half8 __attribute__((ext_vector_type(8)));
typedef float    f32x4 __attribute__((ext_vector_type(4)));

#define N_ROWS 65536
#define DIM    256
#define KCODES 4096
#define BM 128
#define BN 128
#define BK 32
#define NSLICE (DIM / BK)      // 8
#define NCHUNK (KCODES / BN)   // 32

// d_ws layout (bytes): csq[4096]f32 | (gap) | ch[1M]f16 | cl[1M]f16
#define WS_CSQ 0
#define WS_CH  278528
#define WS_CL  2375680

// async global->LDS, 16B per lane, LDS dst = uniform base + lane*16
#define GLDS(g, l) __builtin_amdgcn_global_load_lds(                       \
    (const __attribute__((address_space(1))) unsigned int*)(g),            \
    (__attribute__((address_space(3))) unsigned int*)(l), 16, 0, 0)

// ---- Prologue: csq (k-ascending fmaf chain, matches ref) + cb -> f16 hi/lo planes (x64) ----
__global__ void prep_codes(const float* __restrict__ cb, float* __restrict__ csq,
                           _Float16* __restrict__ ch, _Float16* __restrict__ cl) {
    __shared__ float As[32 * DIM];   // 32KB
    const int t = threadIdx.x;
    const int c0 = blockIdx.x * 32;
    #pragma unroll
    for (int i = 0; i < 8; ++i) {
        int r = 4 * i + (t >> 6), d4 = (t & 63) * 4;
        *(float4*)&As[r * DIM + d4] = *(const float4*)&cb[(size_t)(c0 + r) * DIM + d4];
    }
    __syncthreads();
    {
        const int r = t >> 3;
        const int k0 = (t & 7) * 32;
        const float* src = &As[r * DIM + k0];
        _Float16* dh = &ch[(size_t)(c0 + r) * DIM + k0];
        _Float16* dl = &cl[(size_t)(c0 + r) * DIM + k0];
        #pragma unroll
        for (int i = 0; i < 4; ++i) {
            half8 hv, lv;
            #pragma unroll
            for (int j = 0; j < 8; ++j) {
                float sv = src[i * 8 + j] * 64.f;
                _Float16 h = (_Float16)sv;
                hv[j] = h; lv[j] = (_Float16)(sv - (float)h);
            }
            *(half8*)(dh + i * 8) = hv;
            *(half8*)(dl + i * 8) = lv;
        }
    }
    if (t < 32) {
        const float* row = &As[t * DIM];
        float s = 0.f;
        for (int k = 0; k < DIM; ++k) s = fmaf(row[k], row[k], s);   // k-ascending chain
        csq[c0 + t] = s;
    }
}

// ---- Main: fused x-prep + 3-split f16 MFMA GEMM + fused argmin ----
// A lives in global scratch in FRAG ORDER (per-lane 16B = one MFMA fragment), loaded
// directly to registers (L1/L2-resident, no LDS round trip). LDS carries B only.
// Per slice: [8 ds_read B-frags] [lgkm0+bar] [STAGE B(s+2): 4 GLDS] [sched_bar]
//            [48 MFMA (auto vmcnt wait on A retires older B GLDS)] [A(s+1) loads] [bar]
__global__ __launch_bounds__(256, 2)
void vq_mfma(const float* __restrict__ x, const float* __restrict__ cb,
             const float* __restrict__ csq,
             const _Float16* __restrict__ ch, const _Float16* __restrict__ cl,
             float* out_q, float* __restrict__ out_idx) {
    __shared__ char SMEM[34 * 1024];
    _Float16* BhS = (_Float16*)SMEM;               // [2][BM][BK] = 16KB
    _Float16* BlS = (_Float16*)(SMEM + 16384);     // 16KB
    double*   dtmp = (double*)(SMEM + 32768);      // 1KB (prep)
    float*    xsqS = (float*)(SMEM + 33792);       // 512B (prep)

    const int t = threadIdx.x;
    const int lane = t & 63, wave = t >> 6;
    const int wy = wave >> 1, wx = wave & 1;
    const int m = lane & 15, q = lane >> 4;   // MFMA: A/B row = m, k-granule = q; C: row=4q+e, col=m
    const int n0 = blockIdx.x * BM;
    const int swz = (q ^ (m & 3)) * 8;        // B frag-read granule offset (f16 units)

    // ======== fused x-prep: 4 groups of 32 rows ========
    // A planes -> out_q scratch in FRAG ORDER:
    //   byte addr = blk + ((g2*8 + s)*8 + tr*2 + p)*1024 + q*256 + m*16
    //   (g2=row>>6, tr=(row>>4)&3, m=row&15, s=k>>5, q=(k>>3)&3, p=hi/lo)
    {
        float* prepF = (float*)SMEM;                   // 32KB (B region, free now)
        char*  xqA   = (char*)out_q + ((size_t)n0 << 10);
        for (int g = 0; g < 4; ++g) {
            #pragma unroll
            for (int i = 0; i < 8; ++i) {
                int r = 4 * i + (t >> 6), d4 = (t & 63) * 4;
                *(float4*)&prepF[r * DIM + d4] =
                    *(const float4*)&x[(size_t)(n0 + g * 32 + r) * DIM + d4];
            }
            __syncthreads();
            {
                const int rl   = g * 32 + (t >> 3);     // local row 0..127
                const int g2   = rl >> 6;
                const int tr   = (rl >> 4) & 3;
                const int mm   = rl & 15;
                const int qq   = t & 3;
                const int sbase = (t >> 2) & 1;
                const float* src = &prepF[(t >> 3) * DIM + (t & 7) * 8];
                #pragma unroll
                for (int i = 0; i < 4; ++i) {
                    half8 hv, lv;
                    #pragma unroll
                    for (int j = 0; j < 8; ++j) {
                        float v = src[i * 64 + j];
                        _Float16 h = (_Float16)v;
                        hv[j] = h; lv[j] = (_Float16)(v - (float)h);
                    }
                    const int s_i = sbase + 2 * i;
                    char* dst = xqA + (size_t)(((g2 * 8 + s_i) * 8 + tr * 2) * 1024
                                               + qq * 256 + mm * 16);
                    *(half8*)dst          = hv;          // hi plane (p=0)
                    *(half8*)(dst + 1024) = lv;          // lo plane (p=1)
                }
            }
            if (t < 128) {
                int r = t >> 2, part = t & 3;
                const float* ap = &prepF[r * DIM + 64 * part];
                double s = 0.0;
                for (int k = 0; k < 64; ++k) { double v = (double)ap[k]; s = fma(v, v, s); }
                dtmp[t] = s;
            }
            __syncthreads();
            if (t < 32)
                xsqS[g * 32 + t] = (float)((dtmp[4*t] + dtmp[4*t+1]) + (dtmp[4*t+2] + dtmp[4*t+3]));
            __syncthreads();
        }
    }

    float xsq_r[16];
    #pragma unroll
    for (int s = 0; s < 16; ++s)
        xsq_r[s] = xsqS[64 * wy + 16 * (s >> 2) + 4 * q + (s & 3)];
    // scratch stores must be visible before A loads / staging
    asm volatile("s_waitcnt vmcnt(0)" ::: "memory");
    __syncthreads();

    // ======== B staging addressing (round-1 verified swizzle) ========
    const int rq  = lane >> 2;
    const int gph = lane & 3;
    const int glogB = ((gph ^ (rq & 3)) << 4);  // pre-swizzled source granule, bytes
    const char* bBaseH = (const char*)ch + (((size_t)(wave * 32 + rq)) << 9) + glogB;
    const char* bBaseL = (const char*)cl + (((size_t)(wave * 32 + rq)) << 9) + glogB;
    // A frag-order base: this wave's wy half, per-lane 16B
    const char* ablk = (const char*)out_q + ((size_t)n0 << 10)
                     + (size_t)wy * 65536 + (size_t)lane * 16;

#define STAGE(ck2, sl2, nb) do {                                             \
    const size_t bo_ = ((size_t)(ck2) << 16) + (size_t)((sl2) * 64);         \
    const char* bh_ = bBaseH + bo_;                                          \
    const char* bl_ = bBaseL + bo_;                                          \
    _Float16* Bh_ = BhS + (nb) * (BM * BK) + wave * (32 * BK);               \
    _Float16* Bl_ = BlS + (nb) * (BM * BK) + wave * (32 * BK);               \
    GLDS(bh_,          Bh_);                                                 \
    GLDS(bh_ + 8192,   Bh_ + 16 * BK);                                       \
    GLDS(bl_,          Bl_);                                                 \
    GLDS(bl_ + 8192,   Bl_ + 16 * BK);                                       \
} while (0)

#define ALOAD(asl) do {                                                      \
    _Pragma("unroll")                                                        \
    for (int tr_ = 0; tr_ < 4; ++tr_) {                                      \
        aH[tr_] = *(const half8*)(ablk + (asl) * 8192 + tr_ * 2048);         \
        aL[tr_] = *(const half8*)(ablk + (asl) * 8192 + tr_ * 2048 + 1024);  \
    }                                                                        \
} while (0)

    int boffs[4];
    #pragma unroll
    for (int tc = 0; tc < 4; ++tc) boffs[tc] = (64 * wx + 16 * tc + m) * BK + swz;

    float best[16]; int bidx[16];
    #pragma unroll
    for (int s = 0; s < 16; ++s) { best[s] = FLT_MAX; bidx[s] = 0; }

    half8 aH[4], aL[4], bH[4], bL[4];

    // prologue: B slices 0,1 in flight (order pinned older than A); A(0) to regs;
    // retire B(0) before slice-0 frag reads.
    STAGE(0, 0, 0);
    STAGE(0, 1, 1);
    __builtin_amdgcn_sched_barrier(0);
    ALOAD(0);
    asm volatile("s_waitcnt vmcnt(12)" ::: "memory");
    __builtin_amdgcn_s_barrier();
    __builtin_amdgcn_sched_barrier(0);

    for (int chunk = 0; chunk < NCHUNK; ++chunk) {
        const int c0 = chunk * BN;
        float csq_c[4];
        #pragma unroll
        for (int tc = 0; tc < 4; ++tc) csq_c[tc] = csq[c0 + 64 * wx + 16 * tc + m];

        f32x4 acc[4][4];
        #pragma unroll
        for (int tr = 0; tr < 4; ++tr)
            #pragma unroll
            for (int tc = 0; tc < 4; ++tc) acc[tr][tc] = (f32x4){0.f, 0.f, 0.f, 0.f};

        #pragma unroll
        for (int sl = 0; sl < NSLICE; ++sl) {
            const int cbuf = sl & 1;
            const int sl2r = sl + 2;
            const int ck2 = chunk + (sl2r >> 3);
            const int sl2 = sl2r & 7;
            const bool stg = (ck2 < NCHUNK);
            const bool last = (chunk == NCHUNK - 1) && (sl == NSLICE - 1);

            // 1. B-frag reads for slice s from buf[cbuf]
            {
                const _Float16* Bhr = BhS + cbuf * (BM * BK);
                const _Float16* Blr = BlS + cbuf * (BM * BK);
                #pragma unroll
                for (int tc = 0; tc < 4; ++tc) {
                    bH[tc] = *(const half8*)&Bhr[boffs[tc]];
                    bL[tc] = *(const half8*)&Blr[boffs[tc]];
                }
            }

            // 2. rendezvous + stage B(s+2) into the buffer just read
            if (stg) {
                asm volatile("s_waitcnt lgkmcnt(0)" ::: "memory");
                __builtin_amdgcn_s_barrier();
                __builtin_amdgcn_sched_barrier(0);
                STAGE(ck2, sl2, cbuf);
                __builtin_amdgcn_sched_barrier(0);   // pin: B GLDS older than A loads
            }

            // 3. sweeps HH, HL, LH (bit-exact order). Compiler auto-waits on A(s);
            //    in-order vmcnt retirement also retires B(s+1) before the tail barrier.
            #pragma unroll
            for (int tc = 0; tc < 4; ++tc)
                #pragma unroll
                for (int tr = 0; tr < 4; ++tr)
                    acc[tr][tc] = __builtin_amdgcn_mfma_f32_16x16x32_f16(aH[tr], bH[tc], acc[tr][tc], 0, 0, 0);
            #pragma unroll
            for (int tc = 0; tc < 4; ++tc)
                #pragma unroll
                for (int tr = 0; tr < 4; ++tr)
                    acc[tr][tc] = __builtin_amdgcn_mfma_f32_16x16x32_f16(aH[tr], bL[tc], acc[tr][tc], 0, 0, 0);
            #pragma unroll
            for (int tc = 0; tc < 4; ++tc)
                #pragma unroll
                for (int tr = 0; tr < 4; ++tr)
                    acc[tr][tc] = __builtin_amdgcn_mfma_f32_16x16x32_f16(aL[tr], bH[tc], acc[tr][tc], 0, 0, 0);

            // 4. A-frags for next slice into the now-dead regs (A repeats every chunk)
            if (!last) ALOAD((sl + 1) & 7);

            // 5. chunk epilogue: dist + running argmin (cols ascend)
            if (sl == NSLICE - 1) {
                #pragma unroll
                for (int tc = 0; tc < 4; ++tc) {
                    int c = c0 + 64 * wx + 16 * tc + m;
                    #pragma unroll
                    for (int tr = 0; tr < 4; ++tr) {
                        #pragma unroll
                        for (int e = 0; e < 4; ++e) {
                            float dot = acc[tr][tc][e] * 0.015625f;     // exact /64
                            float d = fmaf(-2.f, dot, xsq_r[tr * 4 + e]) + csq_c[tc];
                            int s = tr * 4 + e;
                            if (d < best[s]) { best[s] = d; bidx[s] = c; }
                        }
                    }
                }
            }

            // 6. tail barrier: every wave has retired B(s+1) (via its A(s) wait),
            //    so buf[(s+1)&1] is globally complete. No manual vmcnt needed.
            if (!last) {
                __builtin_amdgcn_s_barrier();
                __builtin_amdgcn_sched_barrier(0);
            }
        }
    }

    // reduce across the 16 lanes of each quad-group (same physical rows)
    #pragma unroll
    for (int s = 0; s < 16; ++s) {
        float v = best[s]; int idx = bidx[s];
        #pragma unroll
        for (int off = 1; off < 16; off <<= 1) {
            float v2 = __shfl_xor(v, off);
            int   i2 = __shfl_xor(idx, off);
            if (v2 < v || (v2 == v && i2 < idx)) { v = v2; idx = i2; }
        }
        best[s] = v; bidx[s] = idx;
    }
    __syncthreads();                      // staging LDS free now
    float* rb = (float*)SMEM;             // [row][wx] candidates (1KB)
    int*   ri = (int*)(SMEM + 16384);     // (1KB)
    {
        int s = m;                        // lane writes slot == lane&15 (bijective over rows)
        int row_local = 64 * wy + 16 * (s >> 2) + 4 * q + (s & 3);
        rb[row_local * 2 + wx] = best[s];
        ri[row_local * 2 + wx] = bidx[s];
    }
    __syncthreads();
    int* widx = (int*)(SMEM + 32768);
    if (t < BM) {
        float d0 = rb[t * 2], d1 = rb[t * 2 + 1];
        int   i0 = ri[t * 2], i1 = ri[t * 2 + 1];
        int w = (d1 < d0 || (d1 == d0 && i1 < i0)) ? i1 : i0;
        widx[t] = w;
        out_idx[n0 + t] = (float)w;
    }
    __syncthreads();
    // gather winners, coalesced float4 (overwrites this block's packed-A scratch — all A reads done)
    const int l4 = t & 63, rg = t >> 6;
    #pragma unroll 4
    for (int i = 0; i < 32; ++i) {
        int r = rg + 4 * i;
        *(float4*)&out_q[(size_t)(n0 + r) * DIM + l4 * 4] =
            *(const float4*)&cb[(size_t)widx[r] * DIM + l4 * 4];
    }
#undef STAGE
#undef ALOAD
}

extern "C" void kernel_launch(void* const* d_in, const int* in_sizes, int n_in,
                              void* d_out, int out_size, void* d_ws, size_t ws_size,
                              hipStream_t stream) {
    const float* x  = (const float*)d_in[0];
    const float* cb = (const float*)d_in[1];
    float* out_q   = (float*)d_out;
    float* out_idx = (float*)d_out + (size_t)N_ROWS * DIM;

    float*    csq = (float*)((char*)d_ws + WS_CSQ);
    _Float16* ch  = (_Float16*)((char*)d_ws + WS_CH);
    _Float16* cl  = (_Float16*)((char*)d_ws + WS_CL);

    prep_codes<<<KCODES / 32, 256, 0, stream>>>(cb, csq, ch, cl);
    vq_mfma<<<N_ROWS / BM, 256, 0, stream>>>(x, cb, csq, ch, cl, out_q, out_idx);
}

// Round 6
// 578.484 us; speedup vs baseline: 1.3435x; 1.3435x over previous
//
#include <hip/hip_runtime.h>
#include <cfloat>

typedef _Float16 half8 __attribute__((ext_vector_type(8)));
typedef float    f32x4 __attribute__((ext_vector_type(4)));

#define N_ROWS 65536
#define DIM    256
#define KCODES 4096
#define BM 128
#define BN 128
#define BK 32
#define NSLICE (DIM / BK)      // 8
#define NCHUNK (KCODES / BN)   // 32

// d_ws layout (bytes): csq[4096]f32 | (gap) | ch[1M]f16 | cl[1M]f16
#define WS_CSQ 0
#define WS_CH  278528
#define WS_CL  2375680

// async global->LDS, 16B per lane, LDS dst = uniform base + lane*16
#define GLDS(g, l) __builtin_amdgcn_global_load_lds(                       \
    (const __attribute__((address_space(1))) unsigned int*)(g),            \
    (__attribute__((address_space(3))) unsigned int*)(l), 16, 0, 0)

// ---- Prologue: csq (k-ascending fmaf chain, matches ref) + cb -> f16 hi/lo planes (x64) ----
__global__ void prep_codes(const float* __restrict__ cb, float* __restrict__ csq,
                           _Float16* __restrict__ ch, _Float16* __restrict__ cl) {
    __shared__ float As[32 * DIM];   // 32KB
    const int t = threadIdx.x;
    const int c0 = blockIdx.x * 32;
    #pragma unroll
    for (int i = 0; i < 8; ++i) {
        int r = 4 * i + (t >> 6), d4 = (t & 63) * 4;
        *(float4*)&As[r * DIM + d4] = *(const float4*)&cb[(size_t)(c0 + r) * DIM + d4];
    }
    __syncthreads();
    {
        const int r = t >> 3;
        const int k0 = (t & 7) * 32;
        const float* src = &As[r * DIM + k0];
        _Float16* dh = &ch[(size_t)(c0 + r) * DIM + k0];
        _Float16* dl = &cl[(size_t)(c0 + r) * DIM + k0];
        #pragma unroll
        for (int i = 0; i < 4; ++i) {
            half8 hv, lv;
            #pragma unroll
            for (int j = 0; j < 8; ++j) {
                float sv = src[i * 8 + j] * 64.f;
                _Float16 h = (_Float16)sv;
                hv[j] = h; lv[j] = (_Float16)(sv - (float)h);
            }
            *(half8*)(dh + i * 8) = hv;
            *(half8*)(dl + i * 8) = lv;
        }
    }
    if (t < 32) {
        const float* row = &As[t * DIM];
        float s = 0.f;
        for (int k = 0; k < DIM; ++k) s = fmaf(row[k], row[k], s);   // k-ascending chain
        csq[c0 + t] = s;
    }
}

// ---- Main: fused x-prep + 3-split f16 MFMA GEMM + fused argmin ----
// Round-3 schedule (verified 528us): 2-slice-ahead GLDS prefetch on 2 LDS buffers,
// counted vmcnt(8). Per slice: read frags -> lgkm0+bar -> STAGE(s+2) -> MFMA -> vmcnt(8)+bar.
// CHANGE vs round 3: conflict-free granule permutation P(r)=(r+(r>>2))&3 (was r&3).
// Old P gave every 8-lane LDS service group a deterministic 2-way bank conflict
// (lanes m and m+4 shared a bank window); new P makes all 8 windows distinct.
__global__ __launch_bounds__(256, 2)
void vq_mfma(const float* __restrict__ x, const float* __restrict__ cb,
             const float* __restrict__ csq,
             const _Float16* __restrict__ ch, const _Float16* __restrict__ cl,
             float* out_q, float* __restrict__ out_idx) {
    __shared__ _Float16 LDS[8 * BM * BK];          // 64KB total
    _Float16* AhS = LDS;                           // [2][BM][BK]
    _Float16* AlS = LDS + 2 * BM * BK;
    _Float16* BhS = LDS + 4 * BM * BK;
    _Float16* BlS = LDS + 6 * BM * BK;

    const int t = threadIdx.x;
    const int lane = t & 63, wave = t >> 6;
    const int wy = wave >> 1, wx = wave & 1;
    const int m = lane & 15, q = lane >> 4;   // MFMA: A/B row = m, k-granule = q; C: row=4q+e, col=m
    const int n0 = blockIdx.x * BM;
    // conflict-free frag-read granule: slot = q ^ P(row), P(row)=(m + (m>>2)) & 3
    const int swz = (q ^ ((m + (m >> 2)) & 3)) * 8;   // f16 units

    // ======== fused x-prep: 4 groups of 32 rows (verified round 3) ========
    {
        float*  prepF = (float*)LDS;                   // 32KB (AhS+AlS)
        double* dtmp  = (double*)(LDS + 4 * BM * BK);  // 1KB (BhS region)
        float*  xsqS  = (float*)(LDS + 6 * BM * BK);   // 512B (BlS region)
        char*   xqw   = (char*)out_q;
        for (int g = 0; g < 4; ++g) {
            const int r0 = g * 32;
            #pragma unroll
            for (int i = 0; i < 8; ++i) {
                int r = 4 * i + (t >> 6), d4 = (t & 63) * 4;
                *(float4*)&prepF[r * DIM + d4] =
                    *(const float4*)&x[(size_t)(n0 + r0 + r) * DIM + d4];
            }
            __syncthreads();
            {
                const int r = t >> 3;
                const int col8 = (t & 7) * 8;
                char* dst = xqw + (((size_t)(n0 + r0 + r)) << 10) + (size_t)(col8 * 2);
                const float* src = &prepF[r * DIM + col8];
                #pragma unroll
                for (int i = 0; i < 4; ++i) {
                    half8 hv, lv;
                    #pragma unroll
                    for (int j = 0; j < 8; ++j) {
                        float v = src[i * 64 + j];
                        _Float16 h = (_Float16)v;
                        hv[j] = h; lv[j] = (_Float16)(v - (float)h);
                    }
                    *(half8*)(dst + i * 128) = hv;          // hi plane
                    *(half8*)(dst + 512 + i * 128) = lv;    // lo plane
                }
            }
            if (t < 128) {
                int r = t >> 2, part = t & 3;
                const float* ap = &prepF[r * DIM + 64 * part];
                double s = 0.0;
                for (int k = 0; k < 64; ++k) { double v = (double)ap[k]; s = fma(v, v, s); }
                dtmp[t] = s;
            }
            __syncthreads();
            if (t < 32)
                xsqS[r0 + t] = (float)((dtmp[4*t] + dtmp[4*t+1]) + (dtmp[4*t+2] + dtmp[4*t+3]));
            __syncthreads();
        }
    }

    float xsq_r[16];
    {
        const float* xsqS = (const float*)(LDS + 6 * BM * BK);
        #pragma unroll
        for (int s = 0; s < 16; ++s)
            xsq_r[s] = xsqS[64 * wy + 16 * (s >> 2) + 4 * q + (s & 3)];
    }
    // plane stores must be visible before glds reads them back
    asm volatile("s_waitcnt vmcnt(0)" ::: "memory");
    __syncthreads();

    // ======== staging addressing ========
    // lane -> (row rq = lane>>2, LDS slot gs = lane&3); source granule = gs ^ P(rq),
    // P(rq) = (rq + (rq>>2)) & 3  (depends only on rq mod 16 — consistent with read side)
    const int rq  = lane >> 2;
    const int gph = lane & 3;
    const int glogB = ((gph ^ ((rq + (rq >> 2)) & 3)) << 4);  // pre-swizzled source granule, bytes
    const char* xqb = (const char*)out_q;
    const char* aBase  = xqb + (((size_t)(n0 + wave * 32 + rq)) << 10) + glogB;
    const char* bBaseH = (const char*)ch + (((size_t)(wave * 32 + rq)) << 9) + glogB;
    const char* bBaseL = (const char*)cl + (((size_t)(wave * 32 + rq)) << 9) + glogB;

#define STAGE(ck2, sl2, nb) do {                                             \
    const char* a_  = aBase  + (size_t)((sl2) * 64);                         \
    const size_t bo_ = ((size_t)(ck2) << 16) + (size_t)((sl2) * 64);         \
    const char* bh_ = bBaseH + bo_;                                          \
    const char* bl_ = bBaseL + bo_;                                          \
    _Float16* Ah_ = AhS + (nb) * (BM * BK) + wave * (32 * BK);               \
    _Float16* Al_ = AlS + (nb) * (BM * BK) + wave * (32 * BK);               \
    _Float16* Bh_ = BhS + (nb) * (BN * BK) + wave * (32 * BK);               \
    _Float16* Bl_ = BlS + (nb) * (BN * BK) + wave * (32 * BK);               \
    GLDS(a_,           Ah_);                                                 \
    GLDS(a_ + 16384,   Ah_ + 16 * BK);                                       \
    GLDS(a_ + 512,     Al_);                                                 \
    GLDS(a_ + 16896,   Al_ + 16 * BK);                                       \
    GLDS(bh_,          Bh_);                                                 \
    GLDS(bh_ + 8192,   Bh_ + 16 * BK);                                       \
    GLDS(bl_,          Bl_);                                                 \
    GLDS(bl_ + 8192,   Bl_ + 16 * BK);                                       \
} while (0)

    int aoffs[4], boffs[4];
    #pragma unroll
    for (int tr = 0; tr < 4; ++tr) aoffs[tr] = (64 * wy + 16 * tr + m) * BK + swz;
    #pragma unroll
    for (int tc = 0; tc < 4; ++tc) boffs[tc] = (64 * wx + 16 * tc + m) * BK + swz;

    float best[16]; int bidx[16];
    #pragma unroll
    for (int s = 0; s < 16; ++s) { best[s] = FLT_MAX; bidx[s] = 0; }

    // pipeline prologue: slices 0 and 1 in flight; require slice 0 complete
    STAGE(0, 0, 0);
    STAGE(0, 1, 1);
    asm volatile("s_waitcnt vmcnt(8)" ::: "memory");
    __builtin_amdgcn_s_barrier();
    __builtin_amdgcn_sched_barrier(0);

    for (int chunk = 0; chunk < NCHUNK; ++chunk) {
        const int c0 = chunk * BN;
        float csq_c[4];
        #pragma unroll
        for (int tc = 0; tc < 4; ++tc) csq_c[tc] = csq[c0 + 64 * wx + 16 * tc + m];

        f32x4 acc[4][4];
        #pragma unroll
        for (int tr = 0; tr < 4; ++tr)
            #pragma unroll
            for (int tc = 0; tc < 4; ++tc) acc[tr][tc] = (f32x4){0.f, 0.f, 0.f, 0.f};

        #pragma unroll
        for (int sl = 0; sl < NSLICE; ++sl) {
            const int cbuf = sl & 1;
            const _Float16* Ahr = AhS + cbuf * (BM * BK);
            const _Float16* Alr = AlS + cbuf * (BM * BK);
            const _Float16* Bhr = BhS + cbuf * (BN * BK);
            const _Float16* Blr = BlS + cbuf * (BN * BK);

            half8 aH[4], aL[4], bH[4], bL[4];
            #pragma unroll
            for (int tr = 0; tr < 4; ++tr) {
                aH[tr] = *(const half8*)&Ahr[aoffs[tr]];
                aL[tr] = *(const half8*)&Alr[aoffs[tr]];
            }
            #pragma unroll
            for (int tc = 0; tc < 4; ++tc) {
                bH[tc] = *(const half8*)&Bhr[boffs[tc]];
                bL[tc] = *(const half8*)&Blr[boffs[tc]];
            }

            // prefetch slice sl+2 into the buffer we just finished reading
            const int sl2r = sl + 2;
            const int ck2 = chunk + (sl2r >> 3);
            const int sl2 = sl2r & 7;
            const bool stg = (ck2 < NCHUNK);
            if (stg) {
                asm volatile("s_waitcnt lgkmcnt(0)" ::: "memory");  // frags in regs
                __builtin_amdgcn_s_barrier();                        // all waves done reading
                __builtin_amdgcn_sched_barrier(0);
                STAGE(ck2, sl2, cbuf);
            }

            // 3 product sweeps, reuse distance 16 for full MFMA ILP (order = bit-exact)
            #pragma unroll
            for (int tc = 0; tc < 4; ++tc)
                #pragma unroll
                for (int tr = 0; tr < 4; ++tr)
                    acc[tr][tc] = __builtin_amdgcn_mfma_f32_16x16x32_f16(aH[tr], bH[tc], acc[tr][tc], 0, 0, 0);
            #pragma unroll
            for (int tc = 0; tc < 4; ++tc)
                #pragma unroll
                for (int tr = 0; tr < 4; ++tr)
                    acc[tr][tc] = __builtin_amdgcn_mfma_f32_16x16x32_f16(aH[tr], bL[tc], acc[tr][tc], 0, 0, 0);
            #pragma unroll
            for (int tc = 0; tc < 4; ++tc)
                #pragma unroll
                for (int tr = 0; tr < 4; ++tr)
                    acc[tr][tc] = __builtin_amdgcn_mfma_f32_16x16x32_f16(aL[tr], bH[tc], acc[tr][tc], 0, 0, 0);

            if (sl == NSLICE - 1) {
                // chunk epilogue: dist + running argmin (cols ascend)
                #pragma unroll
                for (int tc = 0; tc < 4; ++tc) {
                    int c = c0 + 64 * wx + 16 * tc + m;
                    #pragma unroll
                    for (int tr = 0; tr < 4; ++tr) {
                        #pragma unroll
                        for (int e = 0; e < 4; ++e) {
                            float dot = acc[tr][tc][e] * 0.015625f;     // exact /64
                            float d = fmaf(-2.f, dot, xsq_r[tr * 4 + e]) + csq_c[tc];
                            int s = tr * 4 + e;
                            if (d < best[s]) { best[s] = d; bidx[s] = c; }
                        }
                    }
                }
            }

            if (!(chunk == NCHUNK - 1 && sl == NSLICE - 1)) {
                // counted wait: STAGE(sl+1) (issued a full slice ago) must be done;
                // STAGE(sl+2)'s 8 loads stay in flight.
                if (stg) asm volatile("s_waitcnt vmcnt(8)" ::: "memory");
                else     asm volatile("s_waitcnt vmcnt(0)" ::: "memory");
                __builtin_amdgcn_s_barrier();
                __builtin_amdgcn_sched_barrier(0);
            }
        }
    }

    // reduce across the 16 lanes of each quad-group (same physical rows)
    #pragma unroll
    for (int s = 0; s < 16; ++s) {
        float v = best[s]; int idx = bidx[s];
        #pragma unroll
        for (int off = 1; off < 16; off <<= 1) {
            float v2 = __shfl_xor(v, off);
            int   i2 = __shfl_xor(idx, off);
            if (v2 < v || (v2 == v && i2 < idx)) { v = v2; idx = i2; }
        }
        best[s] = v; bidx[s] = idx;
    }
    __syncthreads();                      // staging LDS free now
    float* rb = (float*)BhS;              // [row][wx] candidates
    int*   ri = (int*)BlS;
    {
        int s = m;                        // lane writes slot == lane&15 (bijective over rows)
        int row_local = 64 * wy + 16 * (s >> 2) + 4 * q + (s & 3);
        rb[row_local * 2 + wx] = best[s];
        ri[row_local * 2 + wx] = bidx[s];
    }
    __syncthreads();
    int* widx = (int*)AhS;
    if (t < BM) {
        float d0 = rb[t * 2], d1 = rb[t * 2 + 1];
        int   i0 = ri[t * 2], i1 = ri[t * 2 + 1];
        int w = (d1 < d0 || (d1 == d0 && i1 < i0)) ? i1 : i0;
        widx[t] = w;
        out_idx[n0 + t] = (float)w;
    }
    __syncthreads();
    // gather winners, coalesced float4 (overwrites this block's packed-x scratch — all A reads done)
    const int l4 = t & 63, rg = t >> 6;
    #pragma unroll 4
    for (int i = 0; i < 32; ++i) {
        int r = rg + 4 * i;
        *(float4*)&out_q[(size_t)(n0 + r) * DIM + l4 * 4] =
            *(const float4*)&cb[(size_t)widx[r] * DIM + l4 * 4];
    }
#undef STAGE
}

extern "C" void kernel_launch(void* const* d_in, const int* in_sizes, int n_in,
                              void* d_out, int out_size, void* d_ws, size_t ws_size,
                              hipStream_t stream) {
    const float* x  = (const float*)d_in[0];
    const float* cb = (const float*)d_in[1];
    float* out_q   = (float*)d_out;
    float* out_idx = (float*)d_out + (size_t)N_ROWS * DIM;

    float*    csq = (float*)((char*)d_ws + WS_CSQ);
    _Float16* ch  = (_Float16*)((char*)d_ws + WS_CH);
    _Float16* cl  = (_Float16*)((char*)d_ws + WS_CL);

    prep_codes<<<KCODES / 32, 256, 0, stream>>>(cb, csq, ch, cl);
    vq_mfma<<<N_ROWS / BM, 256, 0, stream>>>(x, cb, csq, ch, cl, out_q, out_idx);
}

// Round 7
// 576.858 us; speedup vs baseline: 1.3473x; 1.0028x over previous
//
#include <hip/hip_runtime.h>
#include <cfloat>

typedef _Float16 half8 __attribute__((ext_vector_type(8)));
typedef float    f32x4 __attribute__((ext_vector_type(4)));

#define N_ROWS 65536
#define DIM    256
#define KCODES 4096
#define BM 128
#define BN 128
#define BK 32
#define NSLICE (DIM / BK)      // 8
#define NCHUNK (KCODES / BN)   // 32

// d_ws layout (bytes): csq[4096]f32 | (gap) | ch[1M]f16 | cl[1M]f16
#define WS_CSQ 0
#define WS_CH  278528
#define WS_CL  2375680

// async global->LDS, 16B per lane, LDS dst = uniform base + lane*16
#define GLDS(g, l) __builtin_amdgcn_global_load_lds(                       \
    (const __attribute__((address_space(1))) unsigned int*)(g),            \
    (__attribute__((address_space(3))) unsigned int*)(l), 16, 0, 0)

// ---- Prologue: csq (k-ascending fmaf chain, matches ref) + cb -> f16 hi/lo planes (x64) ----
__global__ void prep_codes(const float* __restrict__ cb, float* __restrict__ csq,
                           _Float16* __restrict__ ch, _Float16* __restrict__ cl) {
    __shared__ float As[32 * DIM];   // 32KB
    const int t = threadIdx.x;
    const int c0 = blockIdx.x * 32;
    #pragma unroll
    for (int i = 0; i < 8; ++i) {
        int r = 4 * i + (t >> 6), d4 = (t & 63) * 4;
        *(float4*)&As[r * DIM + d4] = *(const float4*)&cb[(size_t)(c0 + r) * DIM + d4];
    }
    __syncthreads();
    {
        const int r = t >> 3;
        const int k0 = (t & 7) * 32;
        const float* src = &As[r * DIM + k0];
        _Float16* dh = &ch[(size_t)(c0 + r) * DIM + k0];
        _Float16* dl = &cl[(size_t)(c0 + r) * DIM + k0];
        #pragma unroll
        for (int i = 0; i < 4; ++i) {
            half8 hv, lv;
            #pragma unroll
            for (int j = 0; j < 8; ++j) {
                float sv = src[i * 8 + j] * 64.f;
                _Float16 h = (_Float16)sv;
                hv[j] = h; lv[j] = (_Float16)(sv - (float)h);
            }
            *(half8*)(dh + i * 8) = hv;
            *(half8*)(dl + i * 8) = lv;
        }
    }
    if (t < 32) {
        const float* row = &As[t * DIM];
        float s = 0.f;
        for (int k = 0; k < DIM; ++k) s = fmaf(row[k], row[k], s);   // k-ascending chain
        csq[c0 + t] = s;
    }
}

// ---- Main: fused x-prep + 3-split f16 MFMA GEMM + fused argmin ----
// Slice schedule (changed vs round 6 — STAGE moved AFTER the sweeps):
//   [issue 16 ds_reads: aH,bH first] [48 MFMA, compiler staircase lgkmcnt waits]
//   [lgkm0 (free) + vmcnt(0) (retires one-slice-old STAGE(s+1)) + ONE barrier]
//   [STAGE(s+2) into the just-read buffer]
// Read latency hides under MFMA; the old pre-MFMA full LDS drain is gone; 1 barrier/slice.
__global__ __launch_bounds__(256, 2)
void vq_mfma(const float* __restrict__ x, const float* __restrict__ cb,
             const float* __restrict__ csq,
             const _Float16* __restrict__ ch, const _Float16* __restrict__ cl,
             float* out_q, float* __restrict__ out_idx) {
    __shared__ _Float16 LDS[8 * BM * BK];          // 64KB total
    _Float16* AhS = LDS;                           // [2][BM][BK]
    _Float16* AlS = LDS + 2 * BM * BK;
    _Float16* BhS = LDS + 4 * BM * BK;
    _Float16* BlS = LDS + 6 * BM * BK;

    const int t = threadIdx.x;
    const int lane = t & 63, wave = t >> 6;
    const int wy = wave >> 1, wx = wave & 1;
    const int m = lane & 15, q = lane >> 4;   // MFMA: A/B row = m, k-granule = q; C: row=4q+e, col=m
    const int n0 = blockIdx.x * BM;
    const int swz = (q ^ ((m + (m >> 2)) & 3)) * 8;   // frag-read granule offset (f16 units)

    // ======== fused x-prep: 4 groups of 32 rows (verified round 3/6) ========
    {
        float*  prepF = (float*)LDS;                   // 32KB (AhS+AlS)
        double* dtmp  = (double*)(LDS + 4 * BM * BK);  // 1KB (BhS region)
        float*  xsqS  = (float*)(LDS + 6 * BM * BK);   // 512B (BlS region)
        char*   xqw   = (char*)out_q;
        for (int g = 0; g < 4; ++g) {
            const int r0 = g * 32;
            #pragma unroll
            for (int i = 0; i < 8; ++i) {
                int r = 4 * i + (t >> 6), d4 = (t & 63) * 4;
                *(float4*)&prepF[r * DIM + d4] =
                    *(const float4*)&x[(size_t)(n0 + r0 + r) * DIM + d4];
            }
            __syncthreads();
            {
                const int r = t >> 3;
                const int col8 = (t & 7) * 8;
                char* dst = xqw + (((size_t)(n0 + r0 + r)) << 10) + (size_t)(col8 * 2);
                const float* src = &prepF[r * DIM + col8];
                #pragma unroll
                for (int i = 0; i < 4; ++i) {
                    half8 hv, lv;
                    #pragma unroll
                    for (int j = 0; j < 8; ++j) {
                        float v = src[i * 64 + j];
                        _Float16 h = (_Float16)v;
                        hv[j] = h; lv[j] = (_Float16)(v - (float)h);
                    }
                    *(half8*)(dst + i * 128) = hv;          // hi plane
                    *(half8*)(dst + 512 + i * 128) = lv;    // lo plane
                }
            }
            if (t < 128) {
                int r = t >> 2, part = t & 3;
                const float* ap = &prepF[r * DIM + 64 * part];
                double s = 0.0;
                for (int k = 0; k < 64; ++k) { double v = (double)ap[k]; s = fma(v, v, s); }
                dtmp[t] = s;
            }
            __syncthreads();
            if (t < 32)
                xsqS[r0 + t] = (float)((dtmp[4*t] + dtmp[4*t+1]) + (dtmp[4*t+2] + dtmp[4*t+3]));
            __syncthreads();
        }
    }

    float xsq_r[16];
    {
        const float* xsqS = (const float*)(LDS + 6 * BM * BK);
        #pragma unroll
        for (int s = 0; s < 16; ++s)
            xsq_r[s] = xsqS[64 * wy + 16 * (s >> 2) + 4 * q + (s & 3)];
    }
    // plane stores must be visible before glds reads them back
    asm volatile("s_waitcnt vmcnt(0)" ::: "memory");
    __syncthreads();

    // ======== staging addressing (verified) ========
    const int rq  = lane >> 2;
    const int gph = lane & 3;
    const int glogB = ((gph ^ ((rq + (rq >> 2)) & 3)) << 4);  // pre-swizzled source granule, bytes
    const char* xqb = (const char*)out_q;
    const char* aBase  = xqb + (((size_t)(n0 + wave * 32 + rq)) << 10) + glogB;
    const char* bBaseH = (const char*)ch + (((size_t)(wave * 32 + rq)) << 9) + glogB;
    const char* bBaseL = (const char*)cl + (((size_t)(wave * 32 + rq)) << 9) + glogB;

#define STAGE(ck2, sl2, nb) do {                                             \
    const char* a_  = aBase  + (size_t)((sl2) * 64);                         \
    const size_t bo_ = ((size_t)(ck2) << 16) + (size_t)((sl2) * 64);         \
    const char* bh_ = bBaseH + bo_;                                          \
    const char* bl_ = bBaseL + bo_;                                          \
    _Float16* Ah_ = AhS + (nb) * (BM * BK) + wave * (32 * BK);               \
    _Float16* Al_ = AlS + (nb) * (BM * BK) + wave * (32 * BK);               \
    _Float16* Bh_ = BhS + (nb) * (BN * BK) + wave * (32 * BK);               \
    _Float16* Bl_ = BlS + (nb) * (BN * BK) + wave * (32 * BK);               \
    GLDS(a_,           Ah_);                                                 \
    GLDS(a_ + 16384,   Ah_ + 16 * BK);                                       \
    GLDS(a_ + 512,     Al_);                                                 \
    GLDS(a_ + 16896,   Al_ + 16 * BK);                                       \
    GLDS(bh_,          Bh_);                                                 \
    GLDS(bh_ + 8192,   Bh_ + 16 * BK);                                       \
    GLDS(bl_,          Bl_);                                                 \
    GLDS(bl_ + 8192,   Bl_ + 16 * BK);                                       \
} while (0)

    int aoffs[4], boffs[4];
    #pragma unroll
    for (int tr = 0; tr < 4; ++tr) aoffs[tr] = (64 * wy + 16 * tr + m) * BK + swz;
    #pragma unroll
    for (int tc = 0; tc < 4; ++tc) boffs[tc] = (64 * wx + 16 * tc + m) * BK + swz;

    float best[16]; int bidx[16];
    #pragma unroll
    for (int s = 0; s < 16; ++s) { best[s] = FLT_MAX; bidx[s] = 0; }

    // pipeline prologue: slices 0 and 1 in flight; require slice 0 complete
    STAGE(0, 0, 0);
    STAGE(0, 1, 1);
    asm volatile("s_waitcnt vmcnt(8)" ::: "memory");
    __builtin_amdgcn_s_barrier();
    __builtin_amdgcn_sched_barrier(0);

    for (int chunk = 0; chunk < NCHUNK; ++chunk) {
        const int c0 = chunk * BN;
        float csq_c[4];
        #pragma unroll
        for (int tc = 0; tc < 4; ++tc) csq_c[tc] = csq[c0 + 64 * wx + 16 * tc + m];

        f32x4 acc[4][4];
        #pragma unroll
        for (int tr = 0; tr < 4; ++tr)
            #pragma unroll
            for (int tc = 0; tc < 4; ++tc) acc[tr][tc] = (f32x4){0.f, 0.f, 0.f, 0.f};

        #pragma unroll
        for (int sl = 0; sl < NSLICE; ++sl) {
            const int cbuf = sl & 1;
            const _Float16* Ahr = AhS + cbuf * (BM * BK);
            const _Float16* Alr = AlS + cbuf * (BM * BK);
            const _Float16* Bhr = BhS + cbuf * (BN * BK);
            const _Float16* Blr = BlS + cbuf * (BN * BK);

            // frag-read issues: HH operands (aH,bH) first, then bL (HL), then aL (LH)
            // -> compiler emits a staircase of lgkmcnt waits; latency hides under MFMA
            half8 aH[4], aL[4], bH[4], bL[4];
            #pragma unroll
            for (int tr = 0; tr < 4; ++tr) aH[tr] = *(const half8*)&Ahr[aoffs[tr]];
            #pragma unroll
            for (int tc = 0; tc < 4; ++tc) bH[tc] = *(const half8*)&Bhr[boffs[tc]];
            #pragma unroll
            for (int tc = 0; tc < 4; ++tc) bL[tc] = *(const half8*)&Blr[boffs[tc]];
            #pragma unroll
            for (int tr = 0; tr < 4; ++tr) aL[tr] = *(const half8*)&Alr[aoffs[tr]];

            // 3 product sweeps, reuse distance 16 for full MFMA ILP (order = bit-exact)
            #pragma unroll
            for (int tc = 0; tc < 4; ++tc)
                #pragma unroll
                for (int tr = 0; tr < 4; ++tr)
                    acc[tr][tc] = __builtin_amdgcn_mfma_f32_16x16x32_f16(aH[tr], bH[tc], acc[tr][tc], 0, 0, 0);
            #pragma unroll
            for (int tc = 0; tc < 4; ++tc)
                #pragma unroll
                for (int tr = 0; tr < 4; ++tr)
                    acc[tr][tc] = __builtin_amdgcn_mfma_f32_16x16x32_f16(aH[tr], bL[tc], acc[tr][tc], 0, 0, 0);
            #pragma unroll
            for (int tc = 0; tc < 4; ++tc)
                #pragma unroll
                for (int tr = 0; tr < 4; ++tr)
                    acc[tr][tc] = __builtin_amdgcn_mfma_f32_16x16x32_f16(aL[tr], bH[tc], acc[tr][tc], 0, 0, 0);

            // rendezvous + prefetch (single barrier per slice):
            //   lgkm0: our frag reads all consumed (free by now)
            //   vmcnt(0): STAGE(s+1) — issued one slice ago — globally complete after barrier
            //   then overwrite the buffer we just finished reading with slice s+2
            const int sl2r = sl + 2;
            const int ck2 = chunk + (sl2r >> 3);
            const int sl2 = sl2r & 7;
            const bool stg = (ck2 < NCHUNK);
            const bool last = (chunk == NCHUNK - 1) && (sl == NSLICE - 1);
            if (!last) {
                asm volatile("s_waitcnt vmcnt(0) lgkmcnt(0)" ::: "memory");
                __builtin_amdgcn_s_barrier();
                __builtin_amdgcn_sched_barrier(0);
                if (stg) STAGE(ck2, sl2, cbuf);
            }

            if (sl == NSLICE - 1) {
                // chunk epilogue: dist + running argmin (overlaps STAGE flight)
                #pragma unroll
                for (int tc = 0; tc < 4; ++tc) {
                    int c = c0 + 64 * wx + 16 * tc + m;
                    #pragma unroll
                    for (int tr = 0; tr < 4; ++tr) {
                        #pragma unroll
                        for (int e = 0; e < 4; ++e) {
                            float dot = acc[tr][tc][e] * 0.015625f;     // exact /64
                            float d = fmaf(-2.f, dot, xsq_r[tr * 4 + e]) + csq_c[tc];
                            int s = tr * 4 + e;
                            if (d < best[s]) { best[s] = d; bidx[s] = c; }
                        }
                    }
                }
            }
        }
    }

    // reduce across the 16 lanes of each quad-group (same physical rows)
    #pragma unroll
    for (int s = 0; s < 16; ++s) {
        float v = best[s]; int idx = bidx[s];
        #pragma unroll
        for (int off = 1; off < 16; off <<= 1) {
            float v2 = __shfl_xor(v, off);
            int   i2 = __shfl_xor(idx, off);
            if (v2 < v || (v2 == v && i2 < idx)) { v = v2; idx = i2; }
        }
        best[s] = v; bidx[s] = idx;
    }
    __syncthreads();                      // staging LDS free now (implies full waitcnt drain)
    float* rb = (float*)BhS;              // [row][wx] candidates
    int*   ri = (int*)BlS;
    {
        int s = m;                        // lane writes slot == lane&15 (bijective over rows)
        int row_local = 64 * wy + 16 * (s >> 2) + 4 * q + (s & 3);
        rb[row_local * 2 + wx] = best[s];
        ri[row_local * 2 + wx] = bidx[s];
    }
    __syncthreads();
    int* widx = (int*)AhS;
    if (t < BM) {
        float d0 = rb[t * 2], d1 = rb[t * 2 + 1];
        int   i0 = ri[t * 2], i1 = ri[t * 2 + 1];
        int w = (d1 < d0 || (d1 == d0 && i1 < i0)) ? i1 : i0;
        widx[t] = w;
        out_idx[n0 + t] = (float)w;
    }
    __syncthreads();
    // gather winners, coalesced float4 (overwrites this block's packed-x scratch — all A reads done)
    const int l4 = t & 63, rg = t >> 6;
    #pragma unroll 4
    for (int i = 0; i < 32; ++i) {
        int r = rg + 4 * i;
        *(float4*)&out_q[(size_t)(n0 + r) * DIM + l4 * 4] =
            *(const float4*)&cb[(size_t)widx[r] * DIM + l4 * 4];
    }
#undef STAGE
}

extern "C" void kernel_launch(void* const* d_in, const int* in_sizes, int n_in,
                              void* d_out, int out_size, void* d_ws, size_t ws_size,
                              hipStream_t stream) {
    const float* x  = (const float*)d_in[0];
    const float* cb = (const float*)d_in[1];
    float* out_q   = (float*)d_out;
    float* out_idx = (float*)d_out + (size_t)N_ROWS * DIM;

    float*    csq = (float*)((char*)d_ws + WS_CSQ);
    _Float16* ch  = (_Float16*)((char*)d_ws + WS_CH);
    _Float16* cl  = (_Float16*)((char*)d_ws + WS_CL);

    prep_codes<<<KCODES / 32, 256, 0, stream>>>(cb, csq, ch, cl);
    vq_mfma<<<N_ROWS / BM, 256, 0, stream>>>(x, cb, csq, ch, cl, out_q, out_idx);
}